// Round 1
// baseline (303.521 us; speedup 1.0000x reference)
//
#include <hip/hip_runtime.h>
#include <hip/hip_fp16.h>

// Problem constants (B=4, S=8192, IN=OUT=1024, GROUP=128)
#define K_DIM 1024
#define N_DIM 1024

typedef int v4i __attribute__((ext_vector_type(4)));

__device__ __forceinline__ void async_load16(const void* g, void* l) {
    __builtin_amdgcn_global_load_lds(
        (const __attribute__((address_space(1))) unsigned int*)g,
        (__attribute__((address_space(3))) unsigned int*)l,
        16, 0, 0);
}

// Raw barrier (NOT __syncthreads): no compiler-forced vmcnt(0) drain, so
// prefetch loads stay in flight across it. Memory-clobber asm on both sides
// orders all LDS/global memory ops against it.
#define BAR() do { asm volatile("" ::: "memory"); \
                   __builtin_amdgcn_s_barrier();  \
                   asm volatile("" ::: "memory"); } while (0)
#define VMCNT0() asm volatile("s_waitcnt vmcnt(0)" ::: "memory")

// ---------------- Kernel A: weight prep (unchanged, near-roofline) --------
__global__ __launch_bounds__(256) void prep_w(const float* __restrict__ w,
                                              signed char* __restrict__ wq,
                                              float* __restrict__ wscale) {
    const int lane = threadIdx.x & 63;
    const int row  = blockIdx.x * 4 + (threadIdx.x >> 6);
    const float4* wr = (const float4*)(w + (size_t)row * K_DIM);
    float4 v[4];
#pragma unroll
    for (int j = 0; j < 4; ++j) v[j] = wr[lane * 4 + j];

    float g = 0.f;
#pragma unroll
    for (int j = 0; j < 4; ++j) {
        g = fmaxf(g, fabsf(v[j].x)); g = fmaxf(g, fabsf(v[j].y));
        g = fmaxf(g, fabsf(v[j].z)); g = fmaxf(g, fabsf(v[j].w));
    }
    g = fmaxf(g, __shfl_xor(g, 1, 64));
    g = fmaxf(g, __shfl_xor(g, 2, 64));
    g = fmaxf(g, __shfl_xor(g, 4, 64));
    const float s = __half2float(__float2half(fmaxf(g, 1e-8f)));
    float t = s;
    t += __shfl_xor(t, 8, 64);
    t += __shfl_xor(t, 16, 64);
    t += __shfl_xor(t, 32, 64);
    if (lane == 0) wscale[row] = t * 0.125f;

    int pk[4];
#pragma unroll
    for (int j = 0; j < 4; ++j) {
        const int b0 = (v[j].x > 0.f) ? 1 : -1;
        const int b1 = (v[j].y > 0.f) ? 1 : -1;
        const int b2 = (v[j].z > 0.f) ? 1 : -1;
        const int b3 = (v[j].w > 0.f) ? 1 : -1;
        pk[j] = (b0 & 255) | ((b1 & 255) << 8) | ((b2 & 255) << 16) | (b3 << 24);
    }
    *(int4*)(wq + (size_t)row * K_DIM + lane * 16) = make_int4(pk[0], pk[1], pk[2], pk[3]);
}

// ---------------- Kernel B: activation quant (unchanged, near-roofline) ---
__global__ __launch_bounds__(256) void quant_x(const float* __restrict__ x,
                                               signed char* __restrict__ xq,
                                               float* __restrict__ xs) {
    const int lane = threadIdx.x & 63;
    const int row  = blockIdx.x * 4 + (threadIdx.x >> 6);
    const float4* xr = (const float4*)(x + (size_t)row * K_DIM);
    float4 v[4];
#pragma unroll
    for (int j = 0; j < 4; ++j) v[j] = xr[lane * 4 + j];

    float am = 0.f;
#pragma unroll
    for (int j = 0; j < 4; ++j) {
        am = fmaxf(am, fabsf(v[j].x)); am = fmaxf(am, fabsf(v[j].y));
        am = fmaxf(am, fabsf(v[j].z)); am = fmaxf(am, fabsf(v[j].w));
    }
#pragma unroll
    for (int off = 32; off >= 1; off >>= 1) am = fmaxf(am, __shfl_xor(am, off, 64));
    const float scale = fmaxf(am, 1e-8f) / 127.f;
    const float inv   = 1.0f / scale;

    int pk[4];
#pragma unroll
    for (int j = 0; j < 4; ++j) {
        const int b0 = (int)fminf(fmaxf(rintf(v[j].x * inv), -128.f), 127.f);
        const int b1 = (int)fminf(fmaxf(rintf(v[j].y * inv), -128.f), 127.f);
        const int b2 = (int)fminf(fmaxf(rintf(v[j].z * inv), -128.f), 127.f);
        const int b3 = (int)fminf(fmaxf(rintf(v[j].w * inv), -128.f), 127.f);
        pk[j] = (b0 & 255) | ((b1 & 255) << 8) | ((b2 & 255) << 16) | (b3 << 24);
    }
    *(int4*)(xq + (size_t)row * K_DIM + lane * 16) = make_int4(pk[0], pk[1], pk[2], pk[3]);
    if (lane == 0) xs[row] = scale;
}

// ---------------- Kernel C: int8 GEMM, 256x256 tile, prefetch-pipelined ----
// BM=BN=256, BK=64 int8 -> 64B LDS rows. 8 waves (2M x 4N), each wave owns a
// 128x64 output block = acc[8][4] of 16x16 frags via mfma_i32_16x16x64_i8.
// LDS [2 buf][256 rows][64B] per matrix = 64KB total (static-safe).
// 64B rows => ds_read_b128 fragment reads hit all 8 bank-quads evenly:
// quad = (4*r16 + g) & 7  -> conflict-free with NO swizzle; staging is linear
// so global_load_lds width=16 applies directly.
// K-loop: STAGE(t+1 -> other buffer) issued FIRST, then ds_reads + 32 MFMA of
// tile t, then one sched_barrier(0) + vmcnt(0) + raw s_barrier per tile.
// Loads get ~32 MFMAs (~1300 cy) in flight before the wait -> HBM latency
// hidden (T3-minimum recipe; never a zero-gap drain like the old kernel).
__global__ __launch_bounds__(512, 2) void gemm_i8(const signed char* __restrict__ A,
                                                  const signed char* __restrict__ Bw,
                                                  const float* __restrict__ xs,
                                                  const float* __restrict__ wscale,
                                                  const float* __restrict__ bias,
                                                  float* __restrict__ out) {
    __shared__ __align__(16) signed char As[2][256 * 64];
    __shared__ __align__(16) signed char Bs[2][256 * 64];

    const int tid  = threadIdx.x;
    const int lane = tid & 63;
    const int wave = tid >> 6;     // 0..7
    const int wm   = wave >> 2;    // 0..1  (M half)
    const int wn   = wave & 3;     // 0..3  (N quarter)

    // XCD-aware: each XCD gets 64 contiguous wgids = 16 m-tiles x 4 n-tiles,
    // so a 256KB A-panel is fetched into one XCD's L2 and reused 4x.
    const int bid  = blockIdx.x;
    const int wgid = (bid & 7) * 64 + (bid >> 3);   // 512 % 8 == 0: bijective
    const int mT   = wgid >> 2;                     // 0..127
    const int nT   = wgid & 3;                      // 0..3
    const size_t mBase = (size_t)mT * 256;
    const int    nBase = nT * 256;

    // staging: 512 threads x 16B = 8KB = 128 rows x 64B per call; 2 calls per
    // matrix per K-tile. LDS dest linear (tid*16); source row = tid>>2.
    const int srow = tid >> 2;                 // 0..127
    const int skq  = (tid & 3) * 16;           // 0/16/32/48 within BK=64
    const signed char* Ag = A  + (mBase + srow) * K_DIM + skq;
    const signed char* Bg = Bw + (size_t)(nBase + srow) * K_DIM + skq;
    const int soff = tid * 16;

#define STAGE(b, kt) do {                                                   \
        const int _ko = (kt) * 64;                                          \
        async_load16(Ag + _ko,                         &As[b][soff]);       \
        async_load16(Ag + (size_t)128 * K_DIM + _ko,   &As[b][8192 + soff]);\
        async_load16(Bg + _ko,                         &Bs[b][soff]);       \
        async_load16(Bg + (size_t)128 * K_DIM + _ko,   &Bs[b][8192 + soff]);\
    } while (0)

    v4i acc[8][4] = {};

    const int r16 = lane & 15;
    const int g16 = (lane >> 4) * 16;                 // k-chunk within BK
    const int aoff = (wm * 128 + r16) * 64 + g16;
    const int boff = (wn * 64  + r16) * 64 + g16;

    // prologue: stage tile 0, drain once, barrier.
    STAGE(0, 0);
    VMCNT0();
    BAR();

    for (int t = 0; t < 16; ++t) {
        const signed char* Ab = As[t & 1];
        const signed char* Bb = Bs[t & 1];

        if (t < 15) STAGE((t + 1) & 1, t + 1);   // issue next tile ASAP

        v4i af[8], bf[4];
#pragma unroll
        for (int mf = 0; mf < 8; ++mf)
            af[mf] = *(const v4i*)(Ab + aoff + mf * (16 * 64));
#pragma unroll
        for (int nf = 0; nf < 4; ++nf)
            bf[nf] = *(const v4i*)(Bb + boff + nf * (16 * 64));

#pragma unroll
        for (int mf = 0; mf < 8; ++mf)
#pragma unroll
            for (int nf = 0; nf < 4; ++nf)
                acc[mf][nf] = __builtin_amdgcn_mfma_i32_16x16x64_i8(
                    af[mf], bf[nf], acc[mf][nf], 0, 0, 0);

        if (t < 15) {
            // pin all of tile t's MFMAs (and thus their lgkm waits) before the
            // barrier: reg-only MFMAs can otherwise sink past asm fences
            // (guide rule #18) and read LDS being overwritten next tile.
            __builtin_amdgcn_sched_barrier(0);
            VMCNT0();   // only tile t+1's 4 loads outstanding; issued ~32 MFMAs ago
            BAR();
        }
    }
#undef STAGE

    // epilogue: C/D layout col = lane&15, row = (lane>>4)*4 + reg
    const int cc = r16;
    const int rq = (lane >> 4) * 4;
    float xsr[8][4];
#pragma unroll
    for (int mf = 0; mf < 8; ++mf)
#pragma unroll
        for (int i = 0; i < 4; ++i)
            xsr[mf][i] = xs[mBase + wm * 128 + mf * 16 + rq + i];

#pragma unroll
    for (int nf = 0; nf < 4; ++nf) {
        const int col  = nBase + wn * 64 + nf * 16 + cc;
        const float wsc = wscale[col];
        const float bb  = bias[col];
#pragma unroll
        for (int mf = 0; mf < 8; ++mf) {
#pragma unroll
            for (int i = 0; i < 4; ++i) {
                const size_t row = mBase + wm * 128 + mf * 16 + rq + i;
                out[row * N_DIM + col] = (float)acc[mf][nf][i] * xsr[mf][i] * wsc + bb;
            }
        }
    }
}

extern "C" void kernel_launch(void* const* d_in, const int* in_sizes, int n_in,
                              void* d_out, int out_size, void* d_ws, size_t ws_size,
                              hipStream_t stream) {
    const float* x    = (const float*)d_in[0];
    const float* w    = (const float*)d_in[1];
    const float* bias = (const float*)d_in[2];
    float* out = (float*)d_out;

    const int BT = in_sizes[0] / K_DIM;  // 32768 tokens

    // workspace carve
    char* ws = (char*)d_ws;
    signed char* xq     = (signed char*)ws;                                          // BT*1024 B
    float*       xs     = (float*)(ws + (size_t)BT * K_DIM);                         // BT*4 B
    signed char* wq     = (signed char*)(ws + (size_t)BT * K_DIM + (size_t)BT * 4);  // 1 MB
    float*       wscale = (float*)((char*)wq + (size_t)N_DIM * K_DIM);               // 4 KB

    prep_w<<<N_DIM / 4, 256, 0, stream>>>(w, wq, wscale);
    quant_x<<<BT / 4, 256, 0, stream>>>(x, xq, xs);
    gemm_i8<<<(BT / 256) * (N_DIM / 256), 512, 0, stream>>>(xq, wq, xs, wscale, bias, out);
}

// Round 2
// 279.614 us; speedup vs baseline: 1.0855x; 1.0855x over previous
//
#include <hip/hip_runtime.h>
#include <hip/hip_fp16.h>

// Problem constants (B=4, S=8192, IN=OUT=1024, GROUP=128)
#define K_DIM 1024
#define N_DIM 1024

typedef int v4i __attribute__((ext_vector_type(4)));

__device__ __forceinline__ void async_load16(const void* g, void* l) {
    __builtin_amdgcn_global_load_lds(
        (const __attribute__((address_space(1))) unsigned int*)g,
        (__attribute__((address_space(3))) unsigned int*)l,
        16, 0, 0);
}

// Raw barrier: no compiler-forced vmcnt(0) drain, prefetch loads stay in
// flight across it (pattern validated for correctness in the round-1 kernel).
#define BAR() do { asm volatile("" ::: "memory"); \
                   __builtin_amdgcn_s_barrier();  \
                   asm volatile("" ::: "memory"); } while (0)
#define VMCNT0() asm volatile("s_waitcnt vmcnt(0)" ::: "memory")

// ---------------- Kernel A: weight prep (unchanged, ~4 us) ----------------
__global__ __launch_bounds__(256) void prep_w(const float* __restrict__ w,
                                              signed char* __restrict__ wq,
                                              float* __restrict__ wscale) {
    const int lane = threadIdx.x & 63;
    const int row  = blockIdx.x * 4 + (threadIdx.x >> 6);
    const float4* wr = (const float4*)(w + (size_t)row * K_DIM);
    float4 v[4];
#pragma unroll
    for (int j = 0; j < 4; ++j) v[j] = wr[lane * 4 + j];

    float g = 0.f;
#pragma unroll
    for (int j = 0; j < 4; ++j) {
        g = fmaxf(g, fabsf(v[j].x)); g = fmaxf(g, fabsf(v[j].y));
        g = fmaxf(g, fabsf(v[j].z)); g = fmaxf(g, fabsf(v[j].w));
    }
    g = fmaxf(g, __shfl_xor(g, 1, 64));
    g = fmaxf(g, __shfl_xor(g, 2, 64));
    g = fmaxf(g, __shfl_xor(g, 4, 64));
    const float s = __half2float(__float2half(fmaxf(g, 1e-8f)));
    float t = s;
    t += __shfl_xor(t, 8, 64);
    t += __shfl_xor(t, 16, 64);
    t += __shfl_xor(t, 32, 64);
    if (lane == 0) wscale[row] = t * 0.125f;

    int pk[4];
#pragma unroll
    for (int j = 0; j < 4; ++j) {
        const int b0 = (v[j].x > 0.f) ? 1 : -1;
        const int b1 = (v[j].y > 0.f) ? 1 : -1;
        const int b2 = (v[j].z > 0.f) ? 1 : -1;
        const int b3 = (v[j].w > 0.f) ? 1 : -1;
        pk[j] = (b0 & 255) | ((b1 & 255) << 8) | ((b2 & 255) << 16) | (b3 << 24);
    }
    *(int4*)(wq + (size_t)row * K_DIM + lane * 16) = make_int4(pk[0], pk[1], pk[2], pk[3]);
}

// ---------------- Kernel B: fused quant + int8 GEMM ------------------------
// One block per CU (grid=256, 512 thr = 8 waves). Block owns a 128-token
// M-panel and ALL 1024 output cols.
//   Phase 1: quantize own 128 rows of x directly into LDS (As, XOR-swizzled
//            16B chunks so stride-1024 frag reads are bank-uniform).
//            Row scales -> global xsg (tiny), re-read with L1-bypass loads.
//   Phase 2: A resident in LDS (128 KiB). B (1 MiB, L2-hot) streams through
//            a 2x16KiB double buffer. 4 passes of N=256; per pass 16 K-steps
//            (BK=64); wave = 64x64 out = acc[4][4]; 16 MFMA : 8 ds_read_b128
//            per step. Prefetch-early + counted vmcnt(0) + raw barrier.
// LDS total = 128K (As) + 32K (Bs) = 160 KiB exactly -> dynamic shared.
__global__ __launch_bounds__(512, 2) void qgemm(const float* __restrict__ x,
                                                const signed char* __restrict__ Bw,
                                                const float* __restrict__ wscale,
                                                const float* __restrict__ bias,
                                                float* __restrict__ xsg,
                                                float* __restrict__ out) {
    extern __shared__ __align__(16) signed char smem[];
    signed char* As = smem;             // 128 rows x 1024 B (chunk ^= row&7)
    signed char* Bs = smem + 131072;    // [2][256 x 64]

    const int tid  = threadIdx.x;
    const int lane = tid & 63;
    const int wave = tid >> 6;          // 0..7
    const size_t mBase = (size_t)blockIdx.x * 128;

    // ---- Phase 1: quantize rows wave*16 .. wave*16+15 (4-row batches) ----
    for (int rb = 0; rb < 4; ++rb) {
        const int r0 = wave * 16 + rb * 4;
        float4 v[4][4];
#pragma unroll
        for (int rr = 0; rr < 4; ++rr) {
            const float4* xr = (const float4*)(x + (mBase + r0 + rr) * K_DIM);
#pragma unroll
            for (int j = 0; j < 4; ++j) v[rr][j] = xr[lane * 4 + j];
        }
#pragma unroll
        for (int rr = 0; rr < 4; ++rr) {
            const int r = r0 + rr;
            float am = 0.f;
#pragma unroll
            for (int j = 0; j < 4; ++j) {
                am = fmaxf(am, fabsf(v[rr][j].x)); am = fmaxf(am, fabsf(v[rr][j].y));
                am = fmaxf(am, fabsf(v[rr][j].z)); am = fmaxf(am, fabsf(v[rr][j].w));
            }
#pragma unroll
            for (int off = 32; off >= 1; off >>= 1) am = fmaxf(am, __shfl_xor(am, off, 64));
            const float scale = fmaxf(am, 1e-8f) / 127.f;
            const float inv   = 1.0f / scale;   // wave-uniform, one divide
            int pk[4];
#pragma unroll
            for (int j = 0; j < 4; ++j) {
                const int b0 = (int)fminf(fmaxf(rintf(v[rr][j].x * inv), -128.f), 127.f);
                const int b1 = (int)fminf(fmaxf(rintf(v[rr][j].y * inv), -128.f), 127.f);
                const int b2 = (int)fminf(fmaxf(rintf(v[rr][j].z * inv), -128.f), 127.f);
                const int b3 = (int)fminf(fmaxf(rintf(v[rr][j].w * inv), -128.f), 127.f);
                pk[j] = (b0 & 255) | ((b1 & 255) << 8) | ((b2 & 255) << 16) | (b3 << 24);
            }
            // lane holds bytes [lane*16, lane*16+16) of the row = chunk `lane`
            *(int4*)(As + (size_t)r * 1024 + ((lane ^ (r & 7)) * 16)) =
                make_int4(pk[0], pk[1], pk[2], pk[3]);
            if (lane == 0) xsg[mBase + r] = scale;
        }
    }
    __syncthreads();   // full drain: As writes + scale stores visible

    // ---- Phase 2: GEMM ----
    const int wm  = wave >> 2;     // 0..1  (M half: 64 rows)
    const int wn  = wave & 3;      // 0..3  (N quarter within 256-wide pass)
    const int r16 = lane & 15;
    const int g   = lane >> 4;     // k-chunk (16B) within BK=64

    // epilogue scales: same for all passes; L1-bypass (agent) loads since
    // they were stored by other waves on this CU after __syncthreads.
    const int rq = g * 4;
    float xsr[4][4];
#pragma unroll
    for (int mf = 0; mf < 4; ++mf)
#pragma unroll
        for (int i = 0; i < 4; ++i)
            xsr[mf][i] = __hip_atomic_load(&xsg[mBase + wm * 64 + mf * 16 + rq + i],
                                           __ATOMIC_RELAXED, __HIP_MEMORY_SCOPE_AGENT);

    // B staging: 512 thr x 16B = 8KB = 128 rows x 64B per call; 2 calls/tile
    const int srow = tid >> 2;            // 0..127
    const int skq  = (tid & 3) * 16;      // 0/16/32/48 within BK=64
    const int soff = tid * 16;

    for (int p = 0; p < 4; ++p) {
        const int nBase = p * 256;
        const signed char* Bg = Bw + (size_t)(nBase + srow) * K_DIM + skq;

        v4i acc[4][4] = {};

        // prologue: stage K-tile 0 into buf 0
        async_load16(Bg, Bs + soff);
        async_load16(Bg + (size_t)128 * K_DIM, Bs + 8192 + soff);
        VMCNT0();
        BAR();

        for (int t = 0; t < 16; ++t) {
            const signed char* Bb = Bs + (t & 1) * 16384;
            if (t < 15) {   // issue next tile ASAP; lands ~32 MFMAs later
                const int ko = (t + 1) * 64;
                signed char* Bn = Bs + ((t + 1) & 1) * 16384;
                async_load16(Bg + ko, Bn + soff);
                async_load16(Bg + (size_t)128 * K_DIM + ko, Bn + 8192 + soff);
            }
            v4i af[4], bf[4];
#pragma unroll
            for (int mf = 0; mf < 4; ++mf) {
                const int R = wm * 64 + mf * 16 + r16;
                af[mf] = *(const v4i*)(As + (size_t)R * 1024 + (((t * 4 + g) ^ (R & 7)) * 16));
            }
#pragma unroll
            for (int nf = 0; nf < 4; ++nf)
                bf[nf] = *(const v4i*)(Bb + (wn * 64 + nf * 16 + r16) * 64 + g * 16);
#pragma unroll
            for (int mf = 0; mf < 4; ++mf)
#pragma unroll
                for (int nf = 0; nf < 4; ++nf)
                    acc[mf][nf] = __builtin_amdgcn_mfma_i32_16x16x64_i8(
                        af[mf], bf[nf], acc[mf][nf], 0, 0, 0);
            if (t < 15) {
                // pin MFMAs (and their lgkm waits) before the barrier so no
                // wave crosses while still owing reads of this buffer (#18)
                __builtin_amdgcn_sched_barrier(0);
                VMCNT0();   // only next tile's 2 loads outstanding
                BAR();
            }
        }

        // epilogue for this pass: C/D layout col=lane&15, row=(lane>>4)*4+reg
#pragma unroll
        for (int nf = 0; nf < 4; ++nf) {
            const int col   = nBase + wn * 64 + nf * 16 + r16;
            const float wsc = wscale[col];
            const float bb  = bias[col];
#pragma unroll
            for (int mf = 0; mf < 4; ++mf) {
#pragma unroll
                for (int i = 0; i < 4; ++i) {
                    const size_t row = mBase + wm * 64 + mf * 16 + rq + i;
                    out[row * N_DIM + col] = (float)acc[mf][nf][i] * xsr[mf][i] * wsc + bb;
                }
            }
        }
        // no barrier needed: next pass writes buf0, whose last readers (t=14)
        // all passed the t=14-end barrier; t=15 reads buf1 only.
    }
}

extern "C" void kernel_launch(void* const* d_in, const int* in_sizes, int n_in,
                              void* d_out, int out_size, void* d_ws, size_t ws_size,
                              hipStream_t stream) {
    const float* x    = (const float*)d_in[0];
    const float* w    = (const float*)d_in[1];
    const float* bias = (const float*)d_in[2];
    float* out = (float*)d_out;

    const int BT = in_sizes[0] / K_DIM;  // 32768 tokens

    // workspace carve (xq eliminated by fusion)
    char* ws = (char*)d_ws;
    float*       xsg    = (float*)ws;                                  // BT*4 B
    signed char* wq     = (signed char*)(ws + (size_t)BT * 4);         // 1 MB
    float*       wscale = (float*)((char*)wq + (size_t)N_DIM * K_DIM); // 4 KB

    static bool s_attr_set = false;
    if (!s_attr_set) {
        hipFuncSetAttribute((const void*)qgemm,
                            hipFuncAttributeMaxDynamicSharedMemorySize, 163840);
        s_attr_set = true;
    }

    prep_w<<<N_DIM / 4, 256, 0, stream>>>(w, wq, wscale);
    qgemm<<<BT / 128, 512, 163840, stream>>>(x, wq, wscale, bias, xsg, out);
}

// Round 4
// 271.897 us; speedup vs baseline: 1.1163x; 1.0284x over previous
//
#include <hip/hip_runtime.h>
#include <hip/hip_fp16.h>

// Problem constants (B=4, S=8192, IN=OUT=1024, GROUP=128)
#define K_DIM 1024
#define N_DIM 1024

typedef int v4i __attribute__((ext_vector_type(4)));

__device__ __forceinline__ void async_load16(const void* g, void* l) {
    __builtin_amdgcn_global_load_lds(
        (const __attribute__((address_space(1))) unsigned int*)g,
        (__attribute__((address_space(3))) unsigned int*)l,
        16, 0, 0);
}

// Raw barrier: no compiler-forced vmcnt(0) drain, so prefetch loads stay in
// flight across it. "memory" clobbers pin LDS/global *instructions* (not
// completion -> we drain lgkm explicitly before loop-back).
#define BAR() do { asm volatile("" ::: "memory"); \
                   __builtin_amdgcn_s_barrier();  \
                   asm volatile("" ::: "memory"); } while (0)

// ---------------- Kernel A: fused weight prep + activation quant -----------
// Blocks [0,256): prep_w (1024 rows / 4 per block).
// Blocks [256, 256+8192): quant_x (32768 rows / 4 per block).
// Bodies identical to the round-0 near-roofline versions; fusion saves a
// launch gap. Whole blocks take one path -> no divergence.
__global__ __launch_bounds__(256) void prep_quant(const float* __restrict__ w,
                                                  const float* __restrict__ x,
                                                  signed char* __restrict__ wq,
                                                  float* __restrict__ wscale,
                                                  signed char* __restrict__ xq,
                                                  float* __restrict__ xs) {
    const int lane = threadIdx.x & 63;
    if (blockIdx.x < 256) {
        const int row = blockIdx.x * 4 + (threadIdx.x >> 6);
        const float4* wr = (const float4*)(w + (size_t)row * K_DIM);
        float4 v[4];
#pragma unroll
        for (int j = 0; j < 4; ++j) v[j] = wr[lane * 4 + j];

        float g = 0.f;
#pragma unroll
        for (int j = 0; j < 4; ++j) {
            g = fmaxf(g, fabsf(v[j].x)); g = fmaxf(g, fabsf(v[j].y));
            g = fmaxf(g, fabsf(v[j].z)); g = fmaxf(g, fabsf(v[j].w));
        }
        g = fmaxf(g, __shfl_xor(g, 1, 64));
        g = fmaxf(g, __shfl_xor(g, 2, 64));
        g = fmaxf(g, __shfl_xor(g, 4, 64));
        const float s = __half2float(__float2half(fmaxf(g, 1e-8f)));
        float t = s;
        t += __shfl_xor(t, 8, 64);
        t += __shfl_xor(t, 16, 64);
        t += __shfl_xor(t, 32, 64);
        if (lane == 0) wscale[row] = t * 0.125f;

        int pk[4];
#pragma unroll
        for (int j = 0; j < 4; ++j) {
            const int b0 = (v[j].x > 0.f) ? 1 : -1;
            const int b1 = (v[j].y > 0.f) ? 1 : -1;
            const int b2 = (v[j].z > 0.f) ? 1 : -1;
            const int b3 = (v[j].w > 0.f) ? 1 : -1;
            pk[j] = (b0 & 255) | ((b1 & 255) << 8) | ((b2 & 255) << 16) | (b3 << 24);
        }
        *(int4*)(wq + (size_t)row * K_DIM + lane * 16) = make_int4(pk[0], pk[1], pk[2], pk[3]);
    } else {
        const int row = (blockIdx.x - 256) * 4 + (threadIdx.x >> 6);
        const float4* xr = (const float4*)(x + (size_t)row * K_DIM);
        float4 v[4];
#pragma unroll
        for (int j = 0; j < 4; ++j) v[j] = xr[lane * 4 + j];

        float am = 0.f;
#pragma unroll
        for (int j = 0; j < 4; ++j) {
            am = fmaxf(am, fabsf(v[j].x)); am = fmaxf(am, fabsf(v[j].y));
            am = fmaxf(am, fabsf(v[j].z)); am = fmaxf(am, fabsf(v[j].w));
        }
#pragma unroll
        for (int off = 32; off >= 1; off >>= 1) am = fmaxf(am, __shfl_xor(am, off, 64));
        const float scale = fmaxf(am, 1e-8f) / 127.f;
        const float inv   = 1.0f / scale;   // wave-uniform, one divide

        int pk[4];
#pragma unroll
        for (int j = 0; j < 4; ++j) {
            const int b0 = (int)fminf(fmaxf(rintf(v[j].x * inv), -128.f), 127.f);
            const int b1 = (int)fminf(fmaxf(rintf(v[j].y * inv), -128.f), 127.f);
            const int b2 = (int)fminf(fmaxf(rintf(v[j].z * inv), -128.f), 127.f);
            const int b3 = (int)fminf(fmaxf(rintf(v[j].w * inv), -128.f), 127.f);
            pk[j] = (b0 & 255) | ((b1 & 255) << 8) | ((b2 & 255) << 16) | (b3 << 24);
        }
        *(int4*)(xq + (size_t)row * K_DIM + lane * 16) = make_int4(pk[0], pk[1], pk[2], pk[3]);
        if (lane == 0) xs[row] = scale;
    }
}

// ---------------- Kernel B: int8 GEMM, 128x128 tile, triple-buffer depth-2 --
// 256 thr (4 waves 2x2), wave tile 64x64 = acc[4][4], BK=64.
// LDS: 3 x (128x64) x {A,B} = 48 KiB -> 3 blocks/CU (12 waves) at ~100 VGPR.
// Pipeline: prefetch depth 2 with counted vmcnt(4) (never 0 in steady state);
// ONE raw barrier per K-step; lgkmcnt(0) before loop-back guarantees all
// ds_reads of tile t completed before any wave stages into buf[(t+2)%3]
// (= buf[(t-1)%3], last read one step ago, drained pre-barrier).
//
// STAGING OBEYS THE global_load_lds HW RULE (m104/m108): LDS dest is
// wave-uniform base + lane*16 -- so every call uses dest = tid*16 (contiguous
// 4KB across 256 thr = 64 rows x 64B; row = tid>>2, phys chunk = tid&3).
// Round 3's tid*32 double-call pattern violated this and scrambled LDS.
// Swizzle: phys chunk = logical chunk ^ (row&3), applied on the GLOBAL source
// column (dest stays linear) and on ds_read addresses -- same involution both
// sides (rule #21). Rows srow and srow+64 share (row&3) so one scol works.
__global__ __launch_bounds__(256, 3) void gemm_i8(const signed char* __restrict__ A,
                                                  const signed char* __restrict__ Bw,
                                                  const float* __restrict__ xs,
                                                  const float* __restrict__ wscale,
                                                  const float* __restrict__ bias,
                                                  float* __restrict__ out) {
    __shared__ __align__(16) signed char As[3][128 * 64];
    __shared__ __align__(16) signed char Bs[3][128 * 64];

    const int tid  = threadIdx.x;
    const int lane = tid & 63;
    const int wave = tid >> 6;
    const int wm = wave >> 1;   // 0..1
    const int wn = wave & 1;    // 0..1

    // XCD-aware mapping (proven round-0): XCD owns 32 m-tiles x 8 n-tiles so
    // an A-panel lands in one XCD's L2 and is reused for all 8 n-tiles.
    const int bid = blockIdx.x;
    const int xcd = bid & 7;
    const int q   = bid >> 3;            // 0..255
    const int mT  = xcd * 32 + (q >> 3); // 0..255
    const int nT  = q & 7;
    const size_t mBase = (size_t)mT * 128;
    const int    nBase = nT * 128;

    // staging: row = tid>>2, phys chunk = tid&3, source col inverse-swizzled.
    const int srow = tid >> 2;                              // 0..63
    const int scol = ((tid & 3) ^ (srow & 3)) * 16;         // logical source col
    const int soff = tid * 16;                              // linear LDS dest
    const signed char* Ag = A  + (mBase + srow) * K_DIM + scol;
    const signed char* Bg = Bw + (size_t)(nBase + srow) * K_DIM + scol;

#define STAGE(b, kt) do {                                                \
        const int _ko = (kt) * 64;                                       \
        async_load16(Ag + _ko,                      As[b] + soff);       \
        async_load16(Ag + (size_t)64 * K_DIM + _ko, As[b] + 4096 + soff);\
        async_load16(Bg + _ko,                      Bs[b] + soff);       \
        async_load16(Bg + (size_t)64 * K_DIM + _ko, Bs[b] + 4096 + soff);\
    } while (0)

    v4i acc[4][4] = {};
    const int r16 = lane & 15;
    const int g   = lane >> 4;                 // logical 16B k-chunk, 0..3
    const int co  = (g ^ (r16 & 3)) * 16;      // swizzled phys offset (row&3 == r16&3)

    STAGE(0, 0);
    STAGE(1, 1);

    for (int t = 0; t < 16; ++t) {
        // wait for tile t's 4 loads: steady state leaves tile t+1's 4 in flight
        if (t == 15) asm volatile("s_waitcnt vmcnt(0)" ::: "memory");
        else         asm volatile("s_waitcnt vmcnt(4)" ::: "memory");
        BAR();
        if (t < 14) STAGE((t + 2) % 3, t + 2);

        const signed char* Ab = As[t % 3];
        const signed char* Bb = Bs[t % 3];
        v4i af[4], bf[4];
#pragma unroll
        for (int mf = 0; mf < 4; ++mf)
            af[mf] = *(const v4i*)(Ab + ((wm * 64 + mf * 16 + r16) << 6) + co);
#pragma unroll
        for (int nf = 0; nf < 4; ++nf)
            bf[nf] = *(const v4i*)(Bb + ((wn * 64 + nf * 16 + r16) << 6) + co);

#pragma unroll
        for (int mf = 0; mf < 4; ++mf)
#pragma unroll
            for (int nf = 0; nf < 4; ++nf)
                acc[mf][nf] = __builtin_amdgcn_mfma_i32_16x16x64_i8(
                    af[mf], bf[nf], acc[mf][nf], 0, 0, 0);

        // pin instruction order, then require this wave's ds_reads complete
        // before it can cross the next barrier (after which other waves
        // overwrite buf[(t-1)%3]).
        __builtin_amdgcn_sched_barrier(0);
        asm volatile("s_waitcnt lgkmcnt(0)" ::: "memory");
    }
#undef STAGE

    // epilogue: C/D layout col = lane&15, row = (lane>>4)*4 + reg
    const int cc = r16;
    const int rq = (lane >> 4) * 4;
    float xsr[4][4];   // loaded post-loop: no register lifetime across K-loop
#pragma unroll
    for (int mf = 0; mf < 4; ++mf)
#pragma unroll
        for (int i = 0; i < 4; ++i)
            xsr[mf][i] = xs[mBase + wm * 64 + mf * 16 + rq + i];

#pragma unroll
    for (int nf = 0; nf < 4; ++nf) {
        const int col   = nBase + wn * 64 + nf * 16 + cc;
        const float wsc = wscale[col];
        const float bb  = bias[col];
#pragma unroll
        for (int mf = 0; mf < 4; ++mf) {
#pragma unroll
            for (int i = 0; i < 4; ++i) {
                const size_t row = mBase + wm * 64 + mf * 16 + rq + i;
                out[row * N_DIM + col] = (float)acc[mf][nf][i] * xsr[mf][i] * wsc + bb;
            }
        }
    }
}

extern "C" void kernel_launch(void* const* d_in, const int* in_sizes, int n_in,
                              void* d_out, int out_size, void* d_ws, size_t ws_size,
                              hipStream_t stream) {
    const float* x    = (const float*)d_in[0];
    const float* w    = (const float*)d_in[1];
    const float* bias = (const float*)d_in[2];
    float* out = (float*)d_out;

    const int BT = in_sizes[0] / K_DIM;  // 32768 tokens

    // workspace carve
    char* ws = (char*)d_ws;
    signed char* xq     = (signed char*)ws;                                          // BT*1024 B
    float*       xs     = (float*)(ws + (size_t)BT * K_DIM);                         // BT*4 B
    signed char* wq     = (signed char*)(ws + (size_t)BT * K_DIM + (size_t)BT * 4);  // 1 MB
    float*       wscale = (float*)((char*)wq + (size_t)N_DIM * K_DIM);               // 4 KB

    prep_quant<<<256 + BT / 4, 256, 0, stream>>>(w, x, wq, wscale, xq, xs);
    gemm_i8<<<(BT / 128) * (N_DIM / 128), 256, 0, stream>>>(xq, wq, xs, wscale, bias, out);
}